// Round 19
// baseline (248.193 us; speedup 1.0000x reference)
//
#include <hip/hip_runtime.h>
#include <math.h>

// Attend (talking-heads, causal) for B=4,H=16,N=1024,D=64 fp32.
// Round 19: attend_e item width 32 (was 64): 24KB LDS, 4352 uniform WGs,
// tiny prologue (8 K-frags) -> deep co-residency hides per-WG latency.
// attend_pv / prep / E layout unchanged from r16/r17 (191us best).

#define NB 4
#define NH 16
#define NS 1024
#define ND 64
#define IT 16
#define JT 64     // attend_pv step width; E layout unit
#define JTE 32    // attend_e item width
#define NITEM 544
#define HPAD 24
#define PERB_E ((size_t)NITEM * 64 * 256)   // elems per batch

typedef __bf16 bf16x8 __attribute__((ext_vector_type(8)));
typedef __bf16 bf16x4 __attribute__((ext_vector_type(4)));
typedef float  f32x4  __attribute__((ext_vector_type(4)));

__device__ __forceinline__ f32x4 fzero4() {
  f32x4 z; z[0] = 0.f; z[1] = 0.f; z[2] = 0.f; z[3] = 0.f; return z;
}

__device__ __forceinline__ void lgkm_barrier() {
  asm volatile("s_waitcnt lgkmcnt(0)" ::: "memory");
  __builtin_amdgcn_s_barrier();
}

// item q in [0,544) -> (i0, j0) in 64-wide units; r = 4m+t has m+1 chunks.
__device__ __forceinline__ void decode_item(int q, int& i0, int& j0) {
  int m = (int)sqrtf((float)q * 0.5f) + 1;
  while (2 * m * (m + 1) > q) --m;
  while (2 * (m + 1) * (m + 2) <= q) ++m;
  const int off = q - 2 * m * (m + 1);
  const int t = off / (m + 1);
  const int c = off - t * (m + 1);
  i0 = (4 * m + t) * IT;
  j0 = JT * c;
}

__device__ __forceinline__ size_t ebase64(int r) {   // 64-j units before row r
  const int m = r >> 2, t = r & 3;
  return (size_t)(r + 2 * m * (m - 1) + t * m);
}

// ---------------- prep: Qb(1/8), Kb, VT [b,h,d,j], BT[i][j][g] bf16 ----------------
#define QK_BLKS 8192
#define VT_BLKS 1024
#define BT_BLKS 4096

__global__ __launch_bounds__(256)
void prep(const float* __restrict__ Q, const float* __restrict__ K,
          const float* __restrict__ V, const float* __restrict__ Bg,
          __bf16* __restrict__ Qb, __bf16* __restrict__ Kb,
          __bf16* __restrict__ VT, __bf16* __restrict__ BT, int doBT) {
  __shared__ float tile[64][65];
  __shared__ float tmp[16][257];
  const int bid = blockIdx.x;
  const int t = threadIdx.x;
  if (bid < QK_BLKS) {
    const size_t nq4 = (size_t)NB * NH * NS * ND / 4;
    size_t idx = (size_t)bid * 256 + t;
    if (idx < nq4) {
      float4 x = reinterpret_cast<const float4*>(Q)[idx];
      bf16x4 o;
      o[0] = (__bf16)(x.x * 0.125f); o[1] = (__bf16)(x.y * 0.125f);
      o[2] = (__bf16)(x.z * 0.125f); o[3] = (__bf16)(x.w * 0.125f);
      reinterpret_cast<bf16x4*>(Qb)[idx] = o;
    } else {
      idx -= nq4;
      float4 x = reinterpret_cast<const float4*>(K)[idx];
      bf16x4 o;
      o[0] = (__bf16)x.x; o[1] = (__bf16)x.y; o[2] = (__bf16)x.z; o[3] = (__bf16)x.w;
      reinterpret_cast<bf16x4*>(Kb)[idx] = o;
    }
  } else if (bid < QK_BLKS + VT_BLKS) {
    const int vb = bid - QK_BLKS;
    const int bh = vb >> 4;
    const int j0 = (vb & 15) * 64;
    const float* vp = V + ((size_t)bh * NS + j0) * ND;
#pragma unroll
    for (int rep = 0; rep < 4; ++rep) {
      int lin = rep * 256 + t;
      int jj = lin >> 4;
      int dd = (lin & 15) * 4;
      float4 x = *reinterpret_cast<const float4*>(vp + (size_t)jj * ND + dd);
      tile[jj][dd] = x.x; tile[jj][dd + 1] = x.y;
      tile[jj][dd + 2] = x.z; tile[jj][dd + 3] = x.w;
    }
    __syncthreads();
    __bf16* op = VT + (size_t)bh * ND * NS + j0;
#pragma unroll
    for (int rep = 0; rep < 16; ++rep) {
      int lin = rep * 256 + t;
      int d = lin >> 6;
      int jj = lin & 63;
      op[(size_t)d * NS + jj] = (__bf16)tile[jj][d];
    }
  } else if (doBT) {
    const int tb = bid - QK_BLKS - VT_BLKS;   // 0..4095
    const int i = tb >> 2;
    const int j0 = (tb & 3) * 256;
    if (j0 > i) return;
#pragma unroll
    for (int g = 0; g < NH; ++g)
      tmp[g][t] = Bg[(size_t)g * NS * NS + (size_t)i * NS + j0 + t];
    __syncthreads();
    __bf16* op = BT + ((size_t)i * NS + j0) * NH;
#pragma unroll
    for (int rep = 0; rep < 16; ++rep) {
      const int j = rep * 16 + (t >> 4);
      const int g = t & 15;
      op[(size_t)(rep * 256 + t)] = (__bf16)tmp[g][j];
    }
  }
}

// ---------------- kernel 1: E + partial L (one 32-wide chunk per WG) ----------------
template <bool QKWS, bool BTWS>
__global__ __launch_bounds__(512, 4)
void attend_e(const float* __restrict__ Qg, const float* __restrict__ Kg,
              const float* __restrict__ Bg, const float* __restrict__ Wpre,
              const __bf16* __restrict__ Qb, const __bf16* __restrict__ Kb,
              const __bf16* __restrict__ BT,
              __bf16* __restrict__ Ews, float* __restrict__ Lws)
{
  const int bid = blockIdx.x;              // 0..4351
  const int b = bid / (NITEM * 2);
  const int local = bid - b * (NITEM * 2); // 0..1087
  int i0, j064;
  decode_item(NITEM - 1 - (local >> 1), i0, j064);   // heavy rows first
  const int jlo = j064 + (local & 1) * JTE;
  const int r = i0 >> 4;
  const int jmax = ((r >> 2) + 1) * JT;
  __bf16* Eb = Ews + (size_t)b * PERB_E + ebase64(r) * 64 * 256;

  const int tid = threadIdx.x;
  const int w = tid >> 6;
  const int lane = tid & 63;
  const int lr = lane & 15;
  const int lg = lane >> 4;

  __shared__ __align__(16) __bf16 dots[IT * JTE * HPAD];  // 24KB

  // ---- prologue: K (8 frags), Q, bias ----
  bf16x8 kreg[2][2][2];
#pragma unroll
  for (int hh = 0; hh < 2; ++hh) {
    const int h = w + hh * 8;
#pragma unroll
    for (int jb = 0; jb < 2; ++jb)
#pragma unroll
      for (int ks = 0; ks < 2; ++ks) {
        if constexpr (QKWS) {
          kreg[hh][jb][ks] = *reinterpret_cast<const bf16x8*>(
              Kb + ((size_t)(b * NH + h) * NS + jlo + jb * 16 + lr) * ND + ks * 32 + lg * 8);
        } else {
          const float* kp = Kg + ((size_t)(b * NH + h) * NS + jlo + jb * 16 + lr) * ND + ks * 32 + lg * 8;
          float4 x = *reinterpret_cast<const float4*>(kp);
          float4 y = *reinterpret_cast<const float4*>(kp + 4);
          bf16x8 f;
          f[0] = (__bf16)x.x; f[1] = (__bf16)x.y; f[2] = (__bf16)x.z; f[3] = (__bf16)x.w;
          f[4] = (__bf16)y.x; f[5] = (__bf16)y.y; f[6] = (__bf16)y.z; f[7] = (__bf16)y.w;
          kreg[hh][jb][ks] = f;
        }
      }
  }
  bf16x8 qF[2][2];
#pragma unroll
  for (int hh = 0; hh < 2; ++hh) {
    const int h = w + hh * 8;
    if constexpr (QKWS) {
      const __bf16* qp = Qb + ((size_t)(b * NH + h) * NS + i0 + lr) * ND + lg * 8;
      qF[hh][0] = *reinterpret_cast<const bf16x8*>(qp);
      qF[hh][1] = *reinterpret_cast<const bf16x8*>(qp + 32);
    } else {
      const float* qp = Qg + ((size_t)(b * NH + h) * NS + i0 + lr) * ND + lg * 8;
#pragma unroll
      for (int ks = 0; ks < 2; ++ks) {
        float4 x = *reinterpret_cast<const float4*>(qp + ks * 32);
        float4 y = *reinterpret_cast<const float4*>(qp + ks * 32 + 4);
        bf16x8 f;
        f[0] = (__bf16)(x.x * 0.125f); f[1] = (__bf16)(x.y * 0.125f);
        f[2] = (__bf16)(x.z * 0.125f); f[3] = (__bf16)(x.w * 0.125f);
        f[4] = (__bf16)(y.x * 0.125f); f[5] = (__bf16)(y.y * 0.125f);
        f[6] = (__bf16)(y.z * 0.125f); f[7] = (__bf16)(y.w * 0.125f);
        qF[hh][ks] = f;
      }
    }
  }
  bf16x4 braw[2][2];
  float brf[2][2][4];
#pragma unroll
  for (int ii = 0; ii < 2; ++ii) {
    const int gi = i0 + w + ii * 8;
#pragma unroll
    for (int qq = 0; qq < 2; ++qq) {
      if constexpr (BTWS) {
        braw[ii][qq] = *reinterpret_cast<const bf16x4*>(
            BT + ((size_t)gi * NS + jlo + qq * 16 + lr) * NH + lg * 4);
      } else {
#pragma unroll
        for (int rr = 0; rr < 4; ++rr)
          brf[ii][qq][rr] = Bg[((size_t)(lg * 4 + rr) * NS + gi) * NS + jlo + qq * 16 + lr];
      }
    }
  }
  bf16x8 wpreF;   // A-frag, K padded 16->32 (lg>=2 zero)
#pragma unroll
  for (int e = 0; e < 8; ++e) wpreF[e] = (__bf16)0.f;
  if (lg < 2) {
#pragma unroll
    for (int e = 0; e < 8; ++e) wpreF[e] = (__bf16)Wpre[lr * NH + lg * 8 + e];
  }

  // phase1: QK -> dots [c][h], c = i*JTE + j_off
#pragma unroll
  for (int hh = 0; hh < 2; ++hh) {
    const int h = w + hh * 8;
#pragma unroll
    for (int jb = 0; jb < 2; ++jb) {
      f32x4 acc = fzero4();
#pragma unroll
      for (int ks = 0; ks < 2; ++ks)
        acc = __builtin_amdgcn_mfma_f32_16x16x32_bf16(qF[hh][ks], kreg[hh][jb][ks], acc, 0, 0, 0);
#pragma unroll
      for (int rr = 0; rr < 4; ++rr)
        dots[((lg * 4 + rr) * JTE + jb * 16 + lr) * HPAD + h] = (__bf16)acc[rr];
    }
  }
  lgkm_barrier();

  // phase2: mix1 (zero-padded K=32), exp -> L partials + E store [i][j][h]
  float Lp[2][4];
#pragma unroll
  for (int ii = 0; ii < 2; ++ii)
#pragma unroll
    for (int rr = 0; rr < 4; ++rr) Lp[ii][rr] = 0.f;

#pragma unroll
  for (int ii = 0; ii < 2; ++ii) {
    const int i = w + ii * 8;
    const int gi = i0 + i;
#pragma unroll
    for (int qq = 0; qq < 2; ++qq) {
      bf16x8 bfr;
#pragma unroll
      for (int e = 0; e < 8; ++e) bfr[e] = (__bf16)0.f;
      if (lg < 2)
        bfr = *reinterpret_cast<const bf16x8*>(&dots[(i * JTE + qq * 16 + lr) * HPAD + lg * 8]);
      f32x4 s1 = __builtin_amdgcn_mfma_f32_16x16x32_bf16(wpreF, bfr, fzero4(), 0, 0, 0);
      const int gj = jlo + qq * 16 + lr;
      bf16x4 epack;
#pragma unroll
      for (int rr = 0; rr < 4; ++rr) {
        float bv;
        if constexpr (BTWS) bv = (float)braw[ii][qq][rr];
        else                bv = brf[ii][qq][rr];
        float ev = 0.f;
        if (gj <= gi) ev = __expf(s1[rr] + bv);
        Lp[ii][rr] += ev;
        epack[rr] = (__bf16)ev;
      }
      *reinterpret_cast<bf16x4*>(Eb + ((size_t)i * jmax + gj) * 16 + lg * 4) = epack;
    }
  }

#pragma unroll
  for (int ii = 0; ii < 2; ++ii)
#pragma unroll
    for (int rr = 0; rr < 4; ++rr) {
      float v = Lp[ii][rr];
      v += __shfl_xor(v, 1, 64);
      v += __shfl_xor(v, 2, 64);
      v += __shfl_xor(v, 4, 64);
      v += __shfl_xor(v, 8, 64);
      if (lr == 0)
        atomicAdd(&Lws[(size_t)(b * NH + lg * 4 + rr) * NS + i0 + w + ii * 8], v);
    }
}

// ---------------- kernel 2: mix2 + PV; 256 WGs x 1024 thr, dbuf P2 ----------------
template <bool VWS>
__global__ __launch_bounds__(1024)
void attend_pv(const float* __restrict__ Vg, const float* __restrict__ Wpost,
               const __bf16* __restrict__ VTb, const __bf16* __restrict__ Ews,
               const float* __restrict__ Lws, float* __restrict__ Og)
{
  const int bid = blockIdx.x;
  const int x = bid & 7;
  const int q = bid >> 3;
  const int b = x >> 1;
  const int r = 63 - (q * 2 + (x & 1));
  const int i0 = r * IT;
  const int nsteps = (r >> 2) + 1;
  const int jmax = nsteps * JT;
  const __bf16* Eb = Ews + (size_t)b * PERB_E + ebase64(r) * 64 * 256;

  const int tid = threadIdx.x;
  const int w = tid >> 6;
  const int lane = tid & 63;
  const int lr = lane & 15;
  const int lg = lane >> 4;

  __shared__ __align__(16) __bf16 sbP2[2][256 * 64];  // 2 x 32KB, XOR-swizzled

  bf16x8 wpostF;
#pragma unroll
  for (int e = 0; e < 8; ++e) wpostF[e] = (__bf16)0.f;
  if (lg < 2) {
#pragma unroll
    for (int e = 0; e < 8; ++e) {
      const int h = lg * 8 + e;
      const float L = Lws[(size_t)(b * NH + h) * NS + i0 + w];
      wpostF[e] = (__bf16)(Wpost[lr * NH + h] / L);
    }
  }

  f32x4 oacc[4];
#pragma unroll
  for (int db = 0; db < 4; ++db) oacc[db] = fzero4();

  bf16x8 eA[4], eB[4];
  bf16x8 vA[2], vB[2];

  auto load_e = [&](bf16x8 (&buf)[4], int j0) {
#pragma unroll
    for (int qq = 0; qq < 4; ++qq) {
#pragma unroll
      for (int e = 0; e < 8; ++e) buf[qq][e] = (__bf16)0.f;
      if (lg < 2)
        buf[qq] = *reinterpret_cast<const bf16x8*>(
            Eb + ((size_t)w * jmax + j0 + qq * 16 + lr) * 16 + lg * 8);
    }
  };
  auto load_v = [&](bf16x8 (&buf)[2], int j0, int db) {
    if constexpr (VWS) {
      const __bf16* vp = VTb + ((size_t)(b * NH + w) * ND + db * 16 + lr) * NS + j0 + lg * 8;
      buf[0] = *reinterpret_cast<const bf16x8*>(vp);
      buf[1] = *reinterpret_cast<const bf16x8*>(vp + 32);
    } else {
      const float* vp = Vg + (size_t)(b * NH + w) * NS * ND;
      bf16x8 f0, f1;
#pragma unroll
      for (int e = 0; e < 8; ++e) {
        f0[e] = (__bf16)vp[(size_t)(j0 + lg * 8 + e) * ND + db * 16 + lr];
        f1[e] = (__bf16)vp[(size_t)(j0 + 32 + lg * 8 + e) * ND + db * 16 + lr];
      }
      buf[0] = f0; buf[1] = f1;
    }
  };

  auto do_step = [&](int s, bf16x8 (&ecur)[4], bf16x8 (&enxt)[4]) {
    const int cur = s & 1;
    const int j0 = s * JT;
    load_v(vA, j0, 0);
    load_v(vB, j0, 1);
    if (s + 1 < nsteps) load_e(enxt, j0 + JT);
#pragma unroll
    for (int qq = 0; qq < 4; ++qq) {
      f32x4 p2 = __builtin_amdgcn_mfma_f32_16x16x32_bf16(wpostF, ecur[qq], fzero4(), 0, 0, 0);
      const int u = (qq * 16 + lr) >> 3;
#pragma unroll
      for (int rr = 0; rr < 4; ++rr) {
        const int row = (lg * 4 + rr) * IT + w;
        sbP2[cur][row * 64 + ((u ^ (w & 7)) << 3) + (lr & 7)] = (__bf16)p2[rr];
      }
    }
    lgkm_barrier();
    const int row = w * IT + lr;
    const int sw = lr & 7;
    bf16x8 pf0 = *reinterpret_cast<const bf16x8*>(&sbP2[cur][row * 64 + ((lg ^ sw) << 3)]);
    bf16x8 pf1 = *reinterpret_cast<const bf16x8*>(&sbP2[cur][row * 64 + (((4 + lg) ^ sw) << 3)]);
    oacc[0] = __builtin_amdgcn_mfma_f32_16x16x32_bf16(pf0, vA[0], oacc[0], 0, 0, 0);
    oacc[0] = __builtin_amdgcn_mfma_f32_16x16x32_bf16(pf1, vA[1], oacc[0], 0, 0, 0);
    load_v(vA, j0, 2);
    oacc[1] = __builtin_amdgcn_mfma_f32_16x16x32_bf16(pf0, vB[0], oacc[1], 0, 0, 0);
    oacc[1] = __builtin_amdgcn_mfma_f32_16x16x32_bf16(pf1, vB[1], oacc[1], 0, 0, 0);
    load_v(vB, j0, 3);
    oacc[2] = __builtin_amdgcn_mfma_f32_16x16x32_bf16(pf0, vA[0], oacc[2], 0, 0, 0);
    oacc[2] = __builtin_amdgcn_mfma_f32_16x16x32_bf16(pf1, vA[1], oacc[2], 0, 0, 0);
    oacc[3] = __builtin_amdgcn_mfma_f32_16x16x32_bf16(pf0, vB[0], oacc[3], 0, 0, 0);
    oacc[3] = __builtin_amdgcn_mfma_f32_16x16x32_bf16(pf1, vB[1], oacc[3], 0, 0, 0);
  };

  load_e(eA, 0);
  for (int s = 0; s < nsteps; s += 2) {
    do_step(s, eA, eB);
    if (s + 1 < nsteps) do_step(s + 1, eB, eA);
  }

  float* ob = Og + ((size_t)(b * NH + w) * NS + i0) * ND;
#pragma unroll
  for (int db = 0; db < 4; ++db)
#pragma unroll
    for (int rr = 0; rr < 4; ++rr)
      ob[(size_t)(lg * 4 + rr) * ND + db * 16 + lr] = oacc[db][rr];
}

extern "C" void kernel_launch(void* const* d_in, const int* in_sizes, int n_in,
                              void* d_out, int out_size, void* d_ws, size_t ws_size,
                              hipStream_t stream) {
  const float* Q     = (const float*)d_in[0];
  const float* K     = (const float*)d_in[1];
  const float* V     = (const float*)d_in[2];
  const float* BIAS  = (const float*)d_in[3];
  const float* WPRE  = (const float*)d_in[4];
  const float* WPOST = (const float*)d_in[5];
  float* OUT = (float*)d_out;
  (void)in_sizes; (void)n_in; (void)out_size;

  const size_t nelem    = (size_t)NB * NH * NS * ND;      // 4,194,304
  const size_t E_BYTES  = (size_t)NB * PERB_E * 2;        // 71,303,168
  const size_t off_E    = 1u << 20;
  const size_t off_VT   = off_E + E_BYTES;
  const size_t off_Qb   = off_VT + nelem * 2;
  const size_t off_Kb   = off_Qb + nelem * 2;
  const size_t off_BT   = off_Kb + nelem * 2;             // ~97.5 MB
  const size_t BT_BYTES = (size_t)NS * NS * NH * 2;       // 33.6 MB
  const size_t need_full = off_BT + BT_BYTES;             // ~131 MB
  const size_t need_A    = off_BT;                        // ~97.5 MB
  const size_t need_C    = off_VT;                        // ~72.4 MB

  float* Lws = (float*)d_ws;
  hipMemsetAsync(d_ws, 0, (size_t)NB * NH * NS * sizeof(float), stream);

  const int grid_e = NB * NITEM * 2;   // 4352 (32-wide items)
  if (ws_size >= need_C) {
    __bf16* Ews = (__bf16*)((char*)d_ws + off_E);
    if (ws_size >= need_full) {
      __bf16* VT = (__bf16*)((char*)d_ws + off_VT);
      __bf16* Qb = (__bf16*)((char*)d_ws + off_Qb);
      __bf16* Kb = (__bf16*)((char*)d_ws + off_Kb);
      __bf16* BT = (__bf16*)((char*)d_ws + off_BT);
      hipLaunchKernelGGL(prep, dim3(QK_BLKS + VT_BLKS + BT_BLKS), dim3(256), 0, stream,
                         Q, K, V, BIAS, Qb, Kb, VT, BT, 1);
      hipLaunchKernelGGL((attend_e<true, true>), dim3(grid_e), dim3(512), 0, stream,
                         Q, K, BIAS, WPRE, Qb, Kb, BT, Ews, Lws);
      hipLaunchKernelGGL((attend_pv<true>), dim3(NB * 64), dim3(1024), 0, stream,
                         V, WPOST, VT, Ews, Lws, OUT);
    } else if (ws_size >= need_A) {
      __bf16* VT = (__bf16*)((char*)d_ws + off_VT);
      __bf16* Qb = (__bf16*)((char*)d_ws + off_Qb);
      __bf16* Kb = (__bf16*)((char*)d_ws + off_Kb);
      hipLaunchKernelGGL(prep, dim3(QK_BLKS + VT_BLKS), dim3(256), 0, stream,
                         Q, K, V, BIAS, Qb, Kb, VT, (__bf16*)nullptr, 0);
      hipLaunchKernelGGL((attend_e<true, false>), dim3(grid_e), dim3(512), 0, stream,
                         Q, K, BIAS, WPRE, Qb, Kb, (const __bf16*)nullptr, Ews, Lws);
      hipLaunchKernelGGL((attend_pv<true>), dim3(NB * 64), dim3(1024), 0, stream,
                         V, WPOST, VT, Ews, Lws, OUT);
    } else {
      hipLaunchKernelGGL((attend_e<false, false>), dim3(grid_e), dim3(512), 0, stream,
                         Q, K, BIAS, WPRE, (const __bf16*)nullptr, (const __bf16*)nullptr,
                         (const __bf16*)nullptr, Ews, Lws);
      hipLaunchKernelGGL((attend_pv<false>), dim3(NB * 64), dim3(1024), 0, stream,
                         V, WPOST, (const __bf16*)nullptr, Ews, Lws, OUT);
    }
  } else {
    __bf16* Ews = (__bf16*)((char*)d_ws + off_E);
    hipLaunchKernelGGL((attend_e<false, false>), dim3(grid_e), dim3(512), 0, stream,
                       Q, K, BIAS, WPRE, (const __bf16*)nullptr, (const __bf16*)nullptr,
                       (const __bf16*)nullptr, Ews, Lws);
    hipLaunchKernelGGL((attend_pv<false>), dim3(NB * 64), dim3(1024), 0, stream,
                       V, WPOST, (const __bf16*)nullptr, Ews, Lws, OUT);
  }
}

// Round 20
// 186.574 us; speedup vs baseline: 1.3303x; 1.3303x over previous
//
#include <hip/hip_runtime.h>
#include <math.h>

// Attend (talking-heads, causal) for B=4,H=16,N=1024,D=64 fp32.
// Round 20 (r17 base + micro): log2e folded into wpre & BT so exp() becomes
// a bare exp2 (v_exp_f32); Lws zeroed inside prep (one less dispatch).
// Geometry identical to r17 (best: 191.5us).

#define NB 4
#define NH 16
#define NS 1024
#define ND 64
#define IT 16
#define JT 64
#define NITEM 544
#define HPAD 24
#define PERB_E ((size_t)NITEM * 64 * 256)   // elems per batch
#define LOG2E 1.44269504f

typedef __bf16 bf16x8 __attribute__((ext_vector_type(8)));
typedef __bf16 bf16x4 __attribute__((ext_vector_type(4)));
typedef float  f32x4  __attribute__((ext_vector_type(4)));

__device__ __forceinline__ f32x4 fzero4() {
  f32x4 z; z[0] = 0.f; z[1] = 0.f; z[2] = 0.f; z[3] = 0.f; return z;
}

__device__ __forceinline__ void lgkm_barrier() {
  asm volatile("s_waitcnt lgkmcnt(0)" ::: "memory");
  __builtin_amdgcn_s_barrier();
}

// item q in [0,544) -> (i0, j0); r = 4m+t has m+1 chunks.
__device__ __forceinline__ void decode_item(int q, int& i0, int& j0) {
  int m = (int)sqrtf((float)q * 0.5f) + 1;
  while (2 * m * (m + 1) > q) --m;
  while (2 * (m + 1) * (m + 2) <= q) ++m;
  const int off = q - 2 * m * (m + 1);
  const int t = off / (m + 1);
  const int c = off - t * (m + 1);
  i0 = (4 * m + t) * IT;
  j0 = JT * c;
}

__device__ __forceinline__ size_t ebase64(int r) {   // 64-j units before row r
  const int m = r >> 2, t = r & 3;
  return (size_t)(r + 2 * m * (m - 1) + t * m);
}

// ---------------- prep: Qb(1/8), Kb, VT [b,h,d,j], BT[i][j][g]*log2e bf16 ----------------
#define QK_BLKS 8192
#define VT_BLKS 1024
#define BT_BLKS 4096

__global__ __launch_bounds__(256)
void prep(const float* __restrict__ Q, const float* __restrict__ K,
          const float* __restrict__ V, const float* __restrict__ Bg,
          __bf16* __restrict__ Qb, __bf16* __restrict__ Kb,
          __bf16* __restrict__ VT, __bf16* __restrict__ BT, int doBT,
          float* __restrict__ Lz) {
  __shared__ float tile[64][65];
  __shared__ float tmp[16][257];
  const int bid = blockIdx.x;
  const int t = threadIdx.x;
  if (bid < QK_BLKS) {
    if (Lz != nullptr && bid < 256)
      Lz[(size_t)bid * 256 + t] = 0.f;       // 256*256 = NB*NH*NS
    const size_t nq4 = (size_t)NB * NH * NS * ND / 4;
    size_t idx = (size_t)bid * 256 + t;
    if (idx < nq4) {
      float4 x = reinterpret_cast<const float4*>(Q)[idx];
      bf16x4 o;
      o[0] = (__bf16)(x.x * 0.125f); o[1] = (__bf16)(x.y * 0.125f);
      o[2] = (__bf16)(x.z * 0.125f); o[3] = (__bf16)(x.w * 0.125f);
      reinterpret_cast<bf16x4*>(Qb)[idx] = o;
    } else {
      idx -= nq4;
      float4 x = reinterpret_cast<const float4*>(K)[idx];
      bf16x4 o;
      o[0] = (__bf16)x.x; o[1] = (__bf16)x.y; o[2] = (__bf16)x.z; o[3] = (__bf16)x.w;
      reinterpret_cast<bf16x4*>(Kb)[idx] = o;
    }
  } else if (bid < QK_BLKS + VT_BLKS) {
    const int vb = bid - QK_BLKS;
    const int bh = vb >> 4;
    const int j0 = (vb & 15) * 64;
    const float* vp = V + ((size_t)bh * NS + j0) * ND;
#pragma unroll
    for (int rep = 0; rep < 4; ++rep) {
      int lin = rep * 256 + t;
      int jj = lin >> 4;
      int dd = (lin & 15) * 4;
      float4 x = *reinterpret_cast<const float4*>(vp + (size_t)jj * ND + dd);
      tile[jj][dd] = x.x; tile[jj][dd + 1] = x.y;
      tile[jj][dd + 2] = x.z; tile[jj][dd + 3] = x.w;
    }
    __syncthreads();
    __bf16* op = VT + (size_t)bh * ND * NS + j0;
#pragma unroll
    for (int rep = 0; rep < 16; ++rep) {
      int lin = rep * 256 + t;
      int d = lin >> 6;
      int jj = lin & 63;
      op[(size_t)d * NS + jj] = (__bf16)tile[jj][d];
    }
  } else if (doBT) {
    // bias transpose, pre-scaled by log2e: BT[i][j][g] = bias[g][i][j]*LOG2E
    const int tb = bid - QK_BLKS - VT_BLKS;   // 0..4095
    const int i = tb >> 2;
    const int j0 = (tb & 3) * 256;
    if (j0 > i) return;
#pragma unroll
    for (int g = 0; g < NH; ++g)
      tmp[g][t] = Bg[(size_t)g * NS * NS + (size_t)i * NS + j0 + t];
    __syncthreads();
    __bf16* op = BT + ((size_t)i * NS + j0) * NH;
#pragma unroll
    for (int rep = 0; rep < 16; ++rep) {
      const int j = rep * 16 + (t >> 4);
      const int g = t & 15;
      op[(size_t)(rep * 256 + t)] = (__bf16)(tmp[g][j] * LOG2E);
    }
  }
}

// ---------------- kernel 1: E + partial L (one chunk per WG) ----------------
template <bool QKWS, bool BTWS>
__global__ __launch_bounds__(512, 2)
void attend_e(const float* __restrict__ Qg, const float* __restrict__ Kg,
              const float* __restrict__ Bg, const float* __restrict__ Wpre,
              const __bf16* __restrict__ Qb, const __bf16* __restrict__ Kb,
              const __bf16* __restrict__ BT,
              __bf16* __restrict__ Ews, float* __restrict__ Lws)
{
  const int bid = blockIdx.x;
  const int b = bid / NITEM;
  int i0, jlo;
  decode_item(NITEM - 1 - (bid - b * NITEM), i0, jlo);
  const int r = i0 >> 4;
  const int jmax = ((r >> 2) + 1) * JT;
  __bf16* Eb = Ews + (size_t)b * PERB_E + ebase64(r) * 64 * 256;

  const int tid = threadIdx.x;
  const int w = tid >> 6;
  const int lane = tid & 63;
  const int lr = lane & 15;
  const int lg = lane >> 4;

  __shared__ __align__(16) __bf16 dots[IT * JT * HPAD];  // 48KB

  // ---- prologue: K, Q, bias loads ----
  bf16x8 kreg[2][4][2];
#pragma unroll
  for (int hh = 0; hh < 2; ++hh) {
    const int h = w + hh * 8;
#pragma unroll
    for (int jb = 0; jb < 4; ++jb)
#pragma unroll
      for (int ks = 0; ks < 2; ++ks) {
        if constexpr (QKWS) {
          kreg[hh][jb][ks] = *reinterpret_cast<const bf16x8*>(
              Kb + ((size_t)(b * NH + h) * NS + jlo + jb * 16 + lr) * ND + ks * 32 + lg * 8);
        } else {
          const float* kp = Kg + ((size_t)(b * NH + h) * NS + jlo + jb * 16 + lr) * ND + ks * 32 + lg * 8;
          float4 x = *reinterpret_cast<const float4*>(kp);
          float4 y = *reinterpret_cast<const float4*>(kp + 4);
          bf16x8 f;
          f[0] = (__bf16)x.x; f[1] = (__bf16)x.y; f[2] = (__bf16)x.z; f[3] = (__bf16)x.w;
          f[4] = (__bf16)y.x; f[5] = (__bf16)y.y; f[6] = (__bf16)y.z; f[7] = (__bf16)y.w;
          kreg[hh][jb][ks] = f;
        }
      }
  }
  bf16x8 qF[2][2];
#pragma unroll
  for (int hh = 0; hh < 2; ++hh) {
    const int h = w + hh * 8;
    if constexpr (QKWS) {
      const __bf16* qp = Qb + ((size_t)(b * NH + h) * NS + i0 + lr) * ND + lg * 8;
      qF[hh][0] = *reinterpret_cast<const bf16x8*>(qp);
      qF[hh][1] = *reinterpret_cast<const bf16x8*>(qp + 32);
    } else {
      const float* qp = Qg + ((size_t)(b * NH + h) * NS + i0 + lr) * ND + lg * 8;
#pragma unroll
      for (int ks = 0; ks < 2; ++ks) {
        float4 x = *reinterpret_cast<const float4*>(qp + ks * 32);
        float4 y = *reinterpret_cast<const float4*>(qp + ks * 32 + 4);
        bf16x8 f;
        f[0] = (__bf16)(x.x * 0.125f); f[1] = (__bf16)(x.y * 0.125f);
        f[2] = (__bf16)(x.z * 0.125f); f[3] = (__bf16)(x.w * 0.125f);
        f[4] = (__bf16)(y.x * 0.125f); f[5] = (__bf16)(y.y * 0.125f);
        f[6] = (__bf16)(y.z * 0.125f); f[7] = (__bf16)(y.w * 0.125f);
        qF[hh][ks] = f;
      }
    }
  }
  bf16x4 braw[2][4];    // BTWS: dense 8B/lane load (pre-scaled by log2e)
  float brf[2][4][4];   // fp32 fallback (scaled at load)
#pragma unroll
  for (int ii = 0; ii < 2; ++ii) {
    const int gi = i0 + w + ii * 8;
#pragma unroll
    for (int qq = 0; qq < 4; ++qq) {
      if constexpr (BTWS) {
        braw[ii][qq] = *reinterpret_cast<const bf16x4*>(
            BT + ((size_t)gi * NS + jlo + qq * 16 + lr) * NH + lg * 4);
      } else {
#pragma unroll
        for (int rr = 0; rr < 4; ++rr)
          brf[ii][qq][rr] = Bg[((size_t)(lg * 4 + rr) * NS + gi) * NS + jlo + qq * 16 + lr] * LOG2E;
      }
    }
  }
  bf16x8 wpreF;   // A-frag scaled by log2e, K padded 16->32 (lg>=2 zero)
#pragma unroll
  for (int e = 0; e < 8; ++e) wpreF[e] = (__bf16)0.f;
  if (lg < 2) {
#pragma unroll
    for (int e = 0; e < 8; ++e) wpreF[e] = (__bf16)(Wpre[lr * NH + lg * 8 + e] * LOG2E);
  }

  // phase1: QK -> dots [c][h]
#pragma unroll
  for (int hh = 0; hh < 2; ++hh) {
    const int h = w + hh * 8;
#pragma unroll
    for (int jb = 0; jb < 4; ++jb) {
      f32x4 acc = fzero4();
#pragma unroll
      for (int ks = 0; ks < 2; ++ks)
        acc = __builtin_amdgcn_mfma_f32_16x16x32_bf16(qF[hh][ks], kreg[hh][jb][ks], acc, 0, 0, 0);
#pragma unroll
      for (int rr = 0; rr < 4; ++rr)
        dots[((lg * 4 + rr) * JT + jb * 16 + lr) * HPAD + h] = (__bf16)acc[rr];
    }
  }
  lgkm_barrier();

  // phase2: mix1 (scaled), exp2 -> L partials + E store [i][j][h]
  float Lp[2][4];
#pragma unroll
  for (int ii = 0; ii < 2; ++ii)
#pragma unroll
    for (int rr = 0; rr < 4; ++rr) Lp[ii][rr] = 0.f;

#pragma unroll
  for (int ii = 0; ii < 2; ++ii) {
    const int i = w + ii * 8;
    const int gi = i0 + i;
#pragma unroll
    for (int qq = 0; qq < 4; ++qq) {
      bf16x8 bfr;
#pragma unroll
      for (int e = 0; e < 8; ++e) bfr[e] = (__bf16)0.f;
      if (lg < 2)
        bfr = *reinterpret_cast<const bf16x8*>(&dots[(i * JT + qq * 16 + lr) * HPAD + lg * 8]);
      f32x4 s1 = __builtin_amdgcn_mfma_f32_16x16x32_bf16(wpreF, bfr, fzero4(), 0, 0, 0);
      const int gj = jlo + qq * 16 + lr;
      bf16x4 epack;
#pragma unroll
      for (int rr = 0; rr < 4; ++rr) {
        float bv;
        if constexpr (BTWS) bv = (float)braw[ii][qq][rr];
        else                bv = brf[ii][qq][rr];
        float ev = 0.f;
        if (gj <= gi) ev = exp2f(s1[rr] + bv);   // logits pre-scaled by log2e
        Lp[ii][rr] += ev;
        epack[rr] = (__bf16)ev;
      }
      *reinterpret_cast<bf16x4*>(Eb + ((size_t)i * jmax + gj) * 16 + lg * 4) = epack;
    }
  }

#pragma unroll
  for (int ii = 0; ii < 2; ++ii)
#pragma unroll
    for (int rr = 0; rr < 4; ++rr) {
      float v = Lp[ii][rr];
      v += __shfl_xor(v, 1, 64);
      v += __shfl_xor(v, 2, 64);
      v += __shfl_xor(v, 4, 64);
      v += __shfl_xor(v, 8, 64);
      if (lr == 0)
        atomicAdd(&Lws[(size_t)(b * NH + lg * 4 + rr) * NS + i0 + w + ii * 8], v);
    }
}

// ---------------- kernel 2: mix2 + PV; 256 WGs x 1024 thr, dbuf P2 ----------------
template <bool VWS>
__global__ __launch_bounds__(1024)
void attend_pv(const float* __restrict__ Vg, const float* __restrict__ Wpost,
               const __bf16* __restrict__ VTb, const __bf16* __restrict__ Ews,
               const float* __restrict__ Lws, float* __restrict__ Og)
{
  const int bid = blockIdx.x;
  const int x = bid & 7;
  const int q = bid >> 3;
  const int b = x >> 1;
  const int r = 63 - (q * 2 + (x & 1));
  const int i0 = r * IT;
  const int nsteps = (r >> 2) + 1;
  const int jmax = nsteps * JT;
  const __bf16* Eb = Ews + (size_t)b * PERB_E + ebase64(r) * 64 * 256;

  const int tid = threadIdx.x;
  const int w = tid >> 6;
  const int lane = tid & 63;
  const int lr = lane & 15;
  const int lg = lane >> 4;

  __shared__ __align__(16) __bf16 sbP2[2][256 * 64];  // 2 x 32KB, XOR-swizzled

  bf16x8 wpostF;
#pragma unroll
  for (int e = 0; e < 8; ++e) wpostF[e] = (__bf16)0.f;
  if (lg < 2) {
#pragma unroll
    for (int e = 0; e < 8; ++e) {
      const int h = lg * 8 + e;
      const float L = Lws[(size_t)(b * NH + h) * NS + i0 + w];
      wpostF[e] = (__bf16)(Wpost[lr * NH + h] / L);
    }
  }

  f32x4 oacc[4];
#pragma unroll
  for (int db = 0; db < 4; ++db) oacc[db] = fzero4();

  bf16x8 eA[4], eB[4];
  bf16x8 vA[2], vB[2];

  auto load_e = [&](bf16x8 (&buf)[4], int j0) {
#pragma unroll
    for (int qq = 0; qq < 4; ++qq) {
#pragma unroll
      for (int e = 0; e < 8; ++e) buf[qq][e] = (__bf16)0.f;
      if (lg < 2)
        buf[qq] = *reinterpret_cast<const bf16x8*>(
            Eb + ((size_t)w * jmax + j0 + qq * 16 + lr) * 16 + lg * 8);
    }
  };
  auto load_v = [&](bf16x8 (&buf)[2], int j0, int db) {
    if constexpr (VWS) {
      const __bf16* vp = VTb + ((size_t)(b * NH + w) * ND + db * 16 + lr) * NS + j0 + lg * 8;
      buf[0] = *reinterpret_cast<const bf16x8*>(vp);
      buf[1] = *reinterpret_cast<const bf16x8*>(vp + 32);
    } else {
      const float* vp = Vg + (size_t)(b * NH + w) * NS * ND;
      bf16x8 f0, f1;
#pragma unroll
      for (int e = 0; e < 8; ++e) {
        f0[e] = (__bf16)vp[(size_t)(j0 + lg * 8 + e) * ND + db * 16 + lr];
        f1[e] = (__bf16)vp[(size_t)(j0 + 32 + lg * 8 + e) * ND + db * 16 + lr];
      }
      buf[0] = f0; buf[1] = f1;
    }
  };

  auto do_step = [&](int s, bf16x8 (&ecur)[4], bf16x8 (&enxt)[4]) {
    const int cur = s & 1;
    const int j0 = s * JT;
    load_v(vA, j0, 0);
    load_v(vB, j0, 1);
    if (s + 1 < nsteps) load_e(enxt, j0 + JT);
#pragma unroll
    for (int qq = 0; qq < 4; ++qq) {
      f32x4 p2 = __builtin_amdgcn_mfma_f32_16x16x32_bf16(wpostF, ecur[qq], fzero4(), 0, 0, 0);
      const int u = (qq * 16 + lr) >> 3;
#pragma unroll
      for (int rr = 0; rr < 4; ++rr) {
        const int row = (lg * 4 + rr) * IT + w;
        sbP2[cur][row * 64 + ((u ^ (w & 7)) << 3) + (lr & 7)] = (__bf16)p2[rr];
      }
    }
    lgkm_barrier();
    const int row = w * IT + lr;
    const int sw = lr & 7;
    bf16x8 pf0 = *reinterpret_cast<const bf16x8*>(&sbP2[cur][row * 64 + ((lg ^ sw) << 3)]);
    bf16x8 pf1 = *reinterpret_cast<const bf16x8*>(&sbP2[cur][row * 64 + (((4 + lg) ^ sw) << 3)]);
    oacc[0] = __builtin_amdgcn_mfma_f32_16x16x32_bf16(pf0, vA[0], oacc[0], 0, 0, 0);
    oacc[0] = __builtin_amdgcn_mfma_f32_16x16x32_bf16(pf1, vA[1], oacc[0], 0, 0, 0);
    load_v(vA, j0, 2);
    oacc[1] = __builtin_amdgcn_mfma_f32_16x16x32_bf16(pf0, vB[0], oacc[1], 0, 0, 0);
    oacc[1] = __builtin_amdgcn_mfma_f32_16x16x32_bf16(pf1, vB[1], oacc[1], 0, 0, 0);
    load_v(vB, j0, 3);
    oacc[2] = __builtin_amdgcn_mfma_f32_16x16x32_bf16(pf0, vA[0], oacc[2], 0, 0, 0);
    oacc[2] = __builtin_amdgcn_mfma_f32_16x16x32_bf16(pf1, vA[1], oacc[2], 0, 0, 0);
    oacc[3] = __builtin_amdgcn_mfma_f32_16x16x32_bf16(pf0, vB[0], oacc[3], 0, 0, 0);
    oacc[3] = __builtin_amdgcn_mfma_f32_16x16x32_bf16(pf1, vB[1], oacc[3], 0, 0, 0);
  };

  load_e(eA, 0);
  for (int s = 0; s < nsteps; s += 2) {
    do_step(s, eA, eB);
    if (s + 1 < nsteps) do_step(s + 1, eB, eA);
  }

  float* ob = Og + ((size_t)(b * NH + w) * NS + i0) * ND;
#pragma unroll
  for (int db = 0; db < 4; ++db)
#pragma unroll
    for (int rr = 0; rr < 4; ++rr)
      ob[(size_t)(lg * 4 + rr) * ND + db * 16 + lr] = oacc[db][rr];
}

extern "C" void kernel_launch(void* const* d_in, const int* in_sizes, int n_in,
                              void* d_out, int out_size, void* d_ws, size_t ws_size,
                              hipStream_t stream) {
  const float* Q     = (const float*)d_in[0];
  const float* K     = (const float*)d_in[1];
  const float* V     = (const float*)d_in[2];
  const float* BIAS  = (const float*)d_in[3];
  const float* WPRE  = (const float*)d_in[4];
  const float* WPOST = (const float*)d_in[5];
  float* OUT = (float*)d_out;
  (void)in_sizes; (void)n_in; (void)out_size;

  const size_t nelem    = (size_t)NB * NH * NS * ND;      // 4,194,304
  const size_t E_BYTES  = (size_t)NB * PERB_E * 2;        // 71,303,168
  const size_t off_E    = 1u << 20;
  const size_t off_VT   = off_E + E_BYTES;
  const size_t off_Qb   = off_VT + nelem * 2;
  const size_t off_Kb   = off_Qb + nelem * 2;
  const size_t off_BT   = off_Kb + nelem * 2;             // ~97.5 MB
  const size_t BT_BYTES = (size_t)NS * NS * NH * 2;       // 33.6 MB
  const size_t need_full = off_BT + BT_BYTES;             // ~131 MB
  const size_t need_A    = off_BT;                        // ~97.5 MB
  const size_t need_C    = off_VT;                        // ~72.4 MB

  float* Lws = (float*)d_ws;

  const int grid_e = NB * NITEM;   // 2176
  if (ws_size >= need_C) {
    __bf16* Ews = (__bf16*)((char*)d_ws + off_E);
    if (ws_size >= need_full) {
      __bf16* VT = (__bf16*)((char*)d_ws + off_VT);
      __bf16* Qb = (__bf16*)((char*)d_ws + off_Qb);
      __bf16* Kb = (__bf16*)((char*)d_ws + off_Kb);
      __bf16* BT = (__bf16*)((char*)d_ws + off_BT);
      hipLaunchKernelGGL(prep, dim3(QK_BLKS + VT_BLKS + BT_BLKS), dim3(256), 0, stream,
                         Q, K, V, BIAS, Qb, Kb, VT, BT, 1, Lws);
      hipLaunchKernelGGL((attend_e<true, true>), dim3(grid_e), dim3(512), 0, stream,
                         Q, K, BIAS, WPRE, Qb, Kb, BT, Ews, Lws);
      hipLaunchKernelGGL((attend_pv<true>), dim3(NB * 64), dim3(1024), 0, stream,
                         V, WPOST, VT, Ews, Lws, OUT);
    } else if (ws_size >= need_A) {
      __bf16* VT = (__bf16*)((char*)d_ws + off_VT);
      __bf16* Qb = (__bf16*)((char*)d_ws + off_Qb);
      __bf16* Kb = (__bf16*)((char*)d_ws + off_Kb);
      hipLaunchKernelGGL(prep, dim3(QK_BLKS + VT_BLKS), dim3(256), 0, stream,
                         Q, K, V, BIAS, Qb, Kb, VT, (__bf16*)nullptr, 0, Lws);
      hipLaunchKernelGGL((attend_e<true, false>), dim3(grid_e), dim3(512), 0, stream,
                         Q, K, BIAS, WPRE, Qb, Kb, (const __bf16*)nullptr, Ews, Lws);
      hipLaunchKernelGGL((attend_pv<true>), dim3(NB * 64), dim3(1024), 0, stream,
                         V, WPOST, VT, Ews, Lws, OUT);
    } else {
      hipMemsetAsync(d_ws, 0, (size_t)NB * NH * NS * sizeof(float), stream);
      hipLaunchKernelGGL((attend_e<false, false>), dim3(grid_e), dim3(512), 0, stream,
                         Q, K, BIAS, WPRE, (const __bf16*)nullptr, (const __bf16*)nullptr,
                         (const __bf16*)nullptr, Ews, Lws);
      hipLaunchKernelGGL((attend_pv<false>), dim3(NB * 64), dim3(1024), 0, stream,
                         V, WPOST, (const __bf16*)nullptr, Ews, Lws, OUT);
    }
  } else {
    hipMemsetAsync(d_ws, 0, (size_t)NB * NH * NS * sizeof(float), stream);
    __bf16* Ews = (__bf16*)((char*)d_ws + off_E);
    hipLaunchKernelGGL((attend_e<false, false>), dim3(grid_e), dim3(512), 0, stream,
                       Q, K, BIAS, WPRE, (const __bf16*)nullptr, (const __bf16*)nullptr,
                       (const __bf16*)nullptr, Ews, Lws);
    hipLaunchKernelGGL((attend_pv<false>), dim3(NB * 64), dim3(1024), 0, stream,
                       V, WPOST, (const __bf16*)nullptr, Ews, Lws, OUT);
  }
}